// Round 11
// baseline (67.303 us; speedup 1.0000x reference)
//
#include <hip/hip_runtime.h>
#include <stdint.h>

// Problem constants
#define M_ROWS   16000        // B*T
#define D_IN     320
#define E_DIM    16
#define K_CB     8192
#define NCHUNK   32           // k-chunks (16 k-tiles of 16 codewords each)
#define KT_PER_CHUNK 16
#define RPT      4            // row-tiles per wave (pass 1)
#define NRB      63           // row-blocks (16 rt each; 4 rt per wave)

typedef __attribute__((ext_vector_type(8))) short bf16x8;
typedef __attribute__((ext_vector_type(4))) float f32x4;

// Workspace layout (bytes)
#define XA_OFF   0u                 // [1008 tiles][64 lanes][8 bf16]  X (h|m)
#define CBA_OFF  1032192u           // [512 ktiles][64 lanes][8 bf16]  CB (h'|m')
#define XF_OFF   1556480u           // [16000][16] f32 projected rows (exact)
#define MG_OFF   2605056u           // [16000] f32 per-row margin 0.012*||x||
#define PF_OFF   2670592u           // [16000][32] f32 per-chunk approx maxes

#define AS1 __attribute__((address_space(1)))
#define AS3 __attribute__((address_space(3)))

__device__ __forceinline__ unsigned short f2bf(float x) {
    union { float f; unsigned u; } v; v.f = x;
    unsigned r = v.u + 0x7FFFu + ((v.u >> 16) & 1u);   // round-to-nearest-even
    return (unsigned short)(r >> 16);
}
__device__ __forceinline__ float bf2f(unsigned short b) {
    union { unsigned u; float f; } v; v.u = ((unsigned)b) << 16; return v.f;
}

// ---------- Prep: projection + 2-way bf16 split pack + fp32 row + margin
// (blocks 0..249); codebook split pack (blocks 250..377). ----------
__global__ __launch_bounds__(256) void prep_kernel(const float* __restrict__ hs,
                                                   const float* __restrict__ P,
                                                   const float* __restrict__ CB,
                                                   unsigned short* __restrict__ Xa,
                                                   float* __restrict__ Xf,
                                                   float* __restrict__ Mg,
                                                   unsigned short* __restrict__ CBa) {
    int bid = blockIdx.x;
    int t   = threadIdx.x;
    if (bid < 250) {
        int row = bid * 64 + (t >> 2);
        int eq  = t & 3;
        if (row >= M_ROWS) return;
        const float* hrow = hs + (size_t)row * D_IN;
        float ax = 0.f, ay = 0.f, az = 0.f, aw = 0.f;
        #pragma unroll 4
        for (int d = 0; d < D_IN; d += 4) {
            float4 h4 = *reinterpret_cast<const float4*>(hrow + d);
            float4 p0 = *reinterpret_cast<const float4*>(P + (size_t)(d + 0) * E_DIM + eq * 4);
            float4 p1 = *reinterpret_cast<const float4*>(P + (size_t)(d + 1) * E_DIM + eq * 4);
            float4 p2 = *reinterpret_cast<const float4*>(P + (size_t)(d + 2) * E_DIM + eq * 4);
            float4 p3 = *reinterpret_cast<const float4*>(P + (size_t)(d + 3) * E_DIM + eq * 4);
            ax += h4.x * p0.x + h4.y * p1.x + h4.z * p2.x + h4.w * p3.x;
            ay += h4.x * p0.y + h4.y * p1.y + h4.z * p2.y + h4.w * p3.y;
            az += h4.x * p0.z + h4.y * p1.z + h4.z * p2.z + h4.w * p3.z;
            aw += h4.x * p0.w + h4.y * p1.w + h4.z * p2.w + h4.w * p3.w;
        }
        // exact fp32 row for pass-2 rescoring
        *reinterpret_cast<float4*>(Xf + (size_t)row * E_DIM + eq * 4) =
            make_float4(ax, ay, az, aw);
        // per-row margin: M = 0.012 * ||x||  (2B bound with ~50% slack)
        float loc = ax * ax + ay * ay + az * az + aw * aw;
        loc += __shfl_xor(loc, 1, 64);
        loc += __shfl_xor(loc, 2, 64);
        if (eq == 0) Mg[row] = 0.012f * sqrtf(loc);
        // bf16 h|m split pack (A-fragment layout, verified rounds 2-10)
        float v[4] = {ax, ay, az, aw};
        ushort4 h, m;
        unsigned short* hp = (unsigned short*)&h;
        unsigned short* mp = (unsigned short*)&m;
        #pragma unroll
        for (int i = 0; i < 4; ++i) {
            unsigned short hb = f2bf(v[i]);
            unsigned short mb = f2bf(v[i] - bf2f(hb));
            hp[i] = hb; mp[i] = mb;
        }
        int rt = row >> 4, rl = row & 15;
        int g  = eq >> 1;
        int j0 = (eq & 1) * 4;
        size_t base = (size_t)rt * 512;
        *reinterpret_cast<ushort4*>(Xa + base + ((g    ) * 16 + rl) * 8 + j0) = h;
        *reinterpret_cast<ushort4*>(Xa + base + ((2 + g) * 16 + rl) * 8 + j0) = m;
    } else {
        int bid2 = bid - 250;                     // 0..127
        int c  = bid2 * 64 + (t >> 2);
        int eq = t & 3;
        float4 v4 = *reinterpret_cast<const float4*>(CB + (size_t)c * E_DIM + eq * 4);
        float v[4] = {v4.x, v4.y, v4.z, v4.w};
        ushort4 h, m;
        unsigned short* hp = (unsigned short*)&h;
        unsigned short* mp = (unsigned short*)&m;
        #pragma unroll
        for (int i = 0; i < 4; ++i) {
            unsigned short hb = f2bf(v[i]);
            unsigned short mb = f2bf(v[i] - bf2f(hb));
            hp[i] = hb; mp[i] = mb;
        }
        int kt = c >> 4, cl = c & 15;
        int g  = eq >> 1;
        int j0 = (eq & 1) * 4;
        size_t base = (size_t)kt * 512;
        *reinterpret_cast<ushort4*>(CBa + base + ((g    ) * 16 + cl) * 8 + j0) = h;
        *reinterpret_cast<ushort4*>(CBa + base + ((2 + g) * 16 + cl) * 8 + j0) = m;
    }
}

// ---------- Pass 1: approx chunk maxes. approx = hh'+mm' (one MFMA/tile),
// one v_max_f32 per element; no index tracking. 2016 blocks x 256 thr. ----------
__global__ __launch_bounds__(256, 8) void score_kernel(const unsigned short* __restrict__ Xa,
                                                       const unsigned short* __restrict__ CBa,
                                                       float* __restrict__ pf) {
    __shared__ unsigned short sA[KT_PER_CHUNK * 512];   // 16 KB  (h'|m')

    int t    = threadIdx.x;
    int lane = t & 63;
    int w    = t >> 6;                // 0..3
    int flat = blockIdx.x;            // 0..2015
    int xcd  = flat & 7;
    int idx  = flat >> 3;             // 0..251
    int kc   = xcd * 4 + idx / NRB;   // 0..31, clustered per XCD
    int rb   = idx % NRB;             // 0..62
    int rt0  = rb * 16 + w * RPT;

    // A fragments (issue early; overlap with staging)
    bf16x8 a_hm[RPT];
    #pragma unroll
    for (int r = 0; r < RPT; ++r)
        a_hm[r] = *reinterpret_cast<const bf16x8*>(Xa + ((size_t)(rt0 + r) * 64 + lane) * 8);

    // Stage the chunk's B fragments (16 KB) via global_load_lds
    {
        const unsigned char* ga = (const unsigned char*)(CBa + (size_t)kc * KT_PER_CHUNK * 512);
        unsigned char* la = (unsigned char*)sA;
        int wo = w * 1024 + lane * 16;
        #pragma unroll
        for (int q = 0; q < 4; ++q)
            __builtin_amdgcn_global_load_lds((const AS1 void*)(ga + q * 4096 + wo),
                                             (AS3 void*)(la + q * 4096 + w * 1024), 16, 0, 0);
    }

    float best[RPT][4];
    #pragma unroll
    for (int r = 0; r < RPT; ++r)
        #pragma unroll
        for (int i = 0; i < 4; ++i) best[r][i] = -3.0e38f;

    __syncthreads();   // vmcnt drain: staging + A-loads complete

    const bf16x8* sA8 = reinterpret_cast<const bf16x8*>(sA);

    #pragma unroll 2
    for (int kt = 0; kt < KT_PER_CHUNK; ++kt) {
        bf16x8 c1 = sA8[kt * 64 + lane];
        #pragma unroll
        for (int r = 0; r < RPT; ++r) {
            f32x4 acc = {0.f, 0.f, 0.f, 0.f};
            acc = __builtin_amdgcn_mfma_f32_16x16x32_bf16(a_hm[r], c1, acc, 0, 0, 0); // hh'+mm'
            #pragma unroll
            for (int i = 0; i < 4; ++i) best[r][i] = fmaxf(best[r][i], acc[i]);
        }
    }

    // reduce max over the 16 columns; one f32 store per row
    #pragma unroll
    for (int r = 0; r < RPT; ++r) {
        #pragma unroll
        for (int i = 0; i < 4; ++i) {
            float s = best[r][i];
            #pragma unroll
            for (int off = 1; off <= 8; off <<= 1)
                s = fmaxf(s, __shfl_xor(s, off, 64));
            if ((lane & 15) == 0) {
                int row = (rt0 + r) * 16 + (lane >> 4) * 4 + i;
                if (row < M_ROWS) pf[(size_t)row * NCHUNK + kc] = s;
            }
        }
    }
}

// ---------- Pass 2: exact rescore of candidate chunks + argmax ----------
// One wave per row (4000 blocks x 256 thr). Candidate chunk: approx max >=
// global approx max - M_row (provably contains the argmax). Exact fp32 dots,
// first-index tie-break, direct int32 output.
__global__ __launch_bounds__(256) void argmax_kernel(const float* __restrict__ pf,
                                                     const float* __restrict__ Mg,
                                                     const float* __restrict__ Xf,
                                                     const float* __restrict__ CB,
                                                     int* __restrict__ out) {
    int t    = threadIdx.x;
    int lane = t & 63;
    int w    = t >> 6;
    int row  = blockIdx.x * 4 + w;    // < 16000 by grid

    // global approx max over 32 chunk values
    float pv = pf[(size_t)row * NCHUNK + (lane & 31)];
    float gmax = pv;
    #pragma unroll
    for (int off = 1; off <= 16; off <<= 1)
        gmax = fmaxf(gmax, __shfl_xor(gmax, off, 64));
    float thr = gmax - Mg[row];

    // exact row vector
    float4 x0 = *reinterpret_cast<const float4*>(Xf + (size_t)row * E_DIM + 0);
    float4 x1 = *reinterpret_cast<const float4*>(Xf + (size_t)row * E_DIM + 4);
    float4 x2 = *reinterpret_cast<const float4*>(Xf + (size_t)row * E_DIM + 8);
    float4 x3 = *reinterpret_cast<const float4*>(Xf + (size_t)row * E_DIM + 12);

    float bs   = -3.0e38f;
    int   bidx = 0x7FFFFFFF;
    for (int kc = 0; kc < NCHUNK; ++kc) {
        float cm = __shfl(pv, kc, 64);
        if (cm >= thr) {
            #pragma unroll
            for (int j = 0; j < 4; ++j) {
                int cw = kc * 256 + j * 64 + lane;          // coalesced
                const float4* cp = reinterpret_cast<const float4*>(CB + (size_t)cw * E_DIM);
                float4 c0 = cp[0], c1 = cp[1], c2 = cp[2], c3 = cp[3];
                float s = x0.x * c0.x + x0.y * c0.y + x0.z * c0.z + x0.w * c0.w
                        + x1.x * c1.x + x1.y * c1.y + x1.z * c1.z + x1.w * c1.w
                        + x2.x * c2.x + x2.y * c2.y + x2.z * c2.z + x2.w * c2.w
                        + x3.x * c3.x + x3.y * c3.y + x3.z * c3.z + x3.w * c3.w;
                bool take = (s > bs) || (s == bs && cw < bidx);
                bs   = take ? s  : bs;
                bidx = take ? cw : bidx;
            }
        }
    }
    // cross-lane argmax with first-index tie-break
    #pragma unroll
    for (int off = 1; off <= 32; off <<= 1) {
        float os = __shfl_xor(bs, off, 64);
        int   oi = __shfl_xor(bidx, off, 64);
        bool take = (os > bs) || (os == bs && oi < bidx);
        bs   = take ? os : bs;
        bidx = take ? oi : bidx;
    }
    if (lane == 0) out[row] = bidx;
}

extern "C" void kernel_launch(void* const* d_in, const int* in_sizes, int n_in,
                              void* d_out, int out_size, void* d_ws, size_t ws_size,
                              hipStream_t stream) {
    const float* hs = (const float*)d_in[0];   // [8,2000,320]
    const float* P  = (const float*)d_in[1];   // [1,320,16]
    const float* CB = (const float*)d_in[2];   // [1,8192,16]
    int* out = (int*)d_out;                    // [8,1,2000] int32

    char* ws = (char*)d_ws;
    unsigned short* Xa  = (unsigned short*)(ws + XA_OFF);
    unsigned short* CBa = (unsigned short*)(ws + CBA_OFF);
    float* Xf = (float*)(ws + XF_OFF);
    float* Mg = (float*)(ws + MG_OFF);
    float* pf = (float*)(ws + PF_OFF);

    prep_kernel<<<dim3(378), dim3(256), 0, stream>>>(hs, P, CB, Xa, Xf, Mg, CBa);
    score_kernel<<<dim3(NRB * NCHUNK), dim3(256), 0, stream>>>(Xa, CBa, pf);
    argmax_kernel<<<dim3(M_ROWS / 4), dim3(256), 0, stream>>>(pf, Mg, Xf, CB, out);
}

// Round 12
// 63.135 us; speedup vs baseline: 1.0660x; 1.0660x over previous
//
#include <hip/hip_runtime.h>
#include <stdint.h>

// Problem constants
#define M_ROWS   16000        // B*T
#define D_IN     320
#define E_DIM    16
#define K_CB     8192
#define NCHUNK   32           // k-chunks (16 k-tiles of 16 codewords each)
#define KT_PER_CHUNK 16
#define RPT      4            // row-tiles per wave (pass 1)
#define NRB      63           // row-blocks (16 rt each; 4 rt per wave)

typedef __attribute__((ext_vector_type(8))) short bf16x8;
typedef __attribute__((ext_vector_type(4))) float f32x4;

// Workspace layout (bytes)
#define XA_OFF   0u                 // [1008 tiles][64 lanes][8 bf16]  X (h|m)
#define CBA_OFF  1032192u           // [512 ktiles][64 lanes][8 bf16]  CB (h'|m')
#define XF_OFF   1556480u           // [16000][16] f32 projected rows (exact)
#define MG_OFF   2580480u           // [16000] f32 margin = 3e-4*||x||
#define PF_OFF   2644480u           // [16000][32] f32 per-chunk approx maxes

#define AS1 __attribute__((address_space(1)))
#define AS3 __attribute__((address_space(3)))

__device__ __forceinline__ unsigned short f2bf(float x) {
    union { float f; unsigned u; } v; v.f = x;
    unsigned r = v.u + 0x7FFFu + ((v.u >> 16) & 1u);   // round-to-nearest-even
    return (unsigned short)(r >> 16);
}
__device__ __forceinline__ float bf2f(unsigned short b) {
    union { unsigned u; float f; } v; v.u = ((unsigned)b) << 16; return v.f;
}

// ---------- Prep: projection + 2-way bf16 split pack + fp32 row + margin
// (blocks 0..249); codebook split pack (blocks 250..377). ----------
__global__ __launch_bounds__(256) void prep_kernel(const float* __restrict__ hs,
                                                   const float* __restrict__ P,
                                                   const float* __restrict__ CB,
                                                   unsigned short* __restrict__ Xa,
                                                   float* __restrict__ Xf,
                                                   float* __restrict__ Mg,
                                                   unsigned short* __restrict__ CBa) {
    int bid = blockIdx.x;
    int t   = threadIdx.x;
    if (bid < 250) {
        int row = bid * 64 + (t >> 2);
        int eq  = t & 3;
        if (row >= M_ROWS) return;
        const float* hrow = hs + (size_t)row * D_IN;
        float ax = 0.f, ay = 0.f, az = 0.f, aw = 0.f;
        #pragma unroll 4
        for (int d = 0; d < D_IN; d += 4) {
            float4 h4 = *reinterpret_cast<const float4*>(hrow + d);
            float4 p0 = *reinterpret_cast<const float4*>(P + (size_t)(d + 0) * E_DIM + eq * 4);
            float4 p1 = *reinterpret_cast<const float4*>(P + (size_t)(d + 1) * E_DIM + eq * 4);
            float4 p2 = *reinterpret_cast<const float4*>(P + (size_t)(d + 2) * E_DIM + eq * 4);
            float4 p3 = *reinterpret_cast<const float4*>(P + (size_t)(d + 3) * E_DIM + eq * 4);
            ax += h4.x * p0.x + h4.y * p1.x + h4.z * p2.x + h4.w * p3.x;
            ay += h4.x * p0.y + h4.y * p1.y + h4.z * p2.y + h4.w * p3.y;
            az += h4.x * p0.z + h4.y * p1.z + h4.z * p2.z + h4.w * p3.z;
            aw += h4.x * p0.w + h4.y * p1.w + h4.z * p2.w + h4.w * p3.w;
        }
        // exact fp32 row for pass-2 rescoring
        *reinterpret_cast<float4*>(Xf + (size_t)row * E_DIM + eq * 4) =
            make_float4(ax, ay, az, aw);
        // per-row margin: M = 3e-4 * ||x||  (>=30x slack over 2-MFMA error bound)
        float loc = ax * ax + ay * ay + az * az + aw * aw;
        loc += __shfl_xor(loc, 1, 64);
        loc += __shfl_xor(loc, 2, 64);
        if (eq == 0) Mg[row] = 3.0e-4f * sqrtf(loc);
        // bf16 h|m split pack (A-fragment layout, verified rounds 2-11)
        float v[4] = {ax, ay, az, aw};
        ushort4 h, m;
        unsigned short* hp = (unsigned short*)&h;
        unsigned short* mp = (unsigned short*)&m;
        #pragma unroll
        for (int i = 0; i < 4; ++i) {
            unsigned short hb = f2bf(v[i]);
            unsigned short mb = f2bf(v[i] - bf2f(hb));
            hp[i] = hb; mp[i] = mb;
        }
        int rt = row >> 4, rl = row & 15;
        int g  = eq >> 1;
        int j0 = (eq & 1) * 4;
        size_t base = (size_t)rt * 512;
        *reinterpret_cast<ushort4*>(Xa + base + ((g    ) * 16 + rl) * 8 + j0) = h;
        *reinterpret_cast<ushort4*>(Xa + base + ((2 + g) * 16 + rl) * 8 + j0) = m;
    } else {
        int bid2 = bid - 250;                     // 0..127
        int c  = bid2 * 64 + (t >> 2);
        int eq = t & 3;
        float4 v4 = *reinterpret_cast<const float4*>(CB + (size_t)c * E_DIM + eq * 4);
        float v[4] = {v4.x, v4.y, v4.z, v4.w};
        ushort4 h, m;
        unsigned short* hp = (unsigned short*)&h;
        unsigned short* mp = (unsigned short*)&m;
        #pragma unroll
        for (int i = 0; i < 4; ++i) {
            unsigned short hb = f2bf(v[i]);
            unsigned short mb = f2bf(v[i] - bf2f(hb));
            hp[i] = hb; mp[i] = mb;
        }
        int kt = c >> 4, cl = c & 15;
        int g  = eq >> 1;
        int j0 = (eq & 1) * 4;
        size_t base = (size_t)kt * 512;
        *reinterpret_cast<ushort4*>(CBa + base + ((g    ) * 16 + cl) * 8 + j0) = h;
        *reinterpret_cast<ushort4*>(CBa + base + ((2 + g) * 16 + cl) * 8 + j0) = m;
    }
}

// ---------- Pass 1: approx chunk maxes. approx = (h+m)(h'+m') via 2 chained
// MFMAs (c1 + lane^32 c2); one v_max per score; no index tracking. ----------
__global__ __launch_bounds__(256, 4) void score_kernel(const unsigned short* __restrict__ Xa,
                                                       const unsigned short* __restrict__ CBa,
                                                       float* __restrict__ pf) {
    __shared__ unsigned short sA[KT_PER_CHUNK * 512];   // 16 KB  (h'|m')

    int t    = threadIdx.x;
    int lane = t & 63;
    int w    = t >> 6;                // 0..3
    int flat = blockIdx.x;            // 0..2015
    int xcd  = flat & 7;
    int idx  = flat >> 3;             // 0..251
    int kc   = xcd * 4 + idx / NRB;   // 0..31, clustered per XCD
    int rb   = idx % NRB;             // 0..62
    int rt0  = rb * 16 + w * RPT;

    // A fragments (issue early; overlap with staging)
    bf16x8 a_hm[RPT];
    #pragma unroll
    for (int r = 0; r < RPT; ++r)
        a_hm[r] = *reinterpret_cast<const bf16x8*>(Xa + ((size_t)(rt0 + r) * 64 + lane) * 8);

    // Stage the chunk's B fragments (16 KB) via global_load_lds
    {
        const unsigned char* ga = (const unsigned char*)(CBa + (size_t)kc * KT_PER_CHUNK * 512);
        unsigned char* la = (unsigned char*)sA;
        int wo = w * 1024 + lane * 16;
        #pragma unroll
        for (int q = 0; q < 4; ++q)
            __builtin_amdgcn_global_load_lds((const AS1 void*)(ga + q * 4096 + wo),
                                             (AS3 void*)(la + q * 4096 + w * 1024), 16, 0, 0);
    }

    float best[RPT][4];
    #pragma unroll
    for (int r = 0; r < RPT; ++r)
        #pragma unroll
        for (int i = 0; i < 4; ++i) best[r][i] = -3.0e38f;

    __syncthreads();   // vmcnt drain: staging + A-loads complete

    const bf16x8* sA8 = reinterpret_cast<const bf16x8*>(sA);
    int lsw = lane ^ 32;

    #pragma unroll 2
    for (int kt = 0; kt < KT_PER_CHUNK; ++kt) {
        bf16x8 c1 = sA8[kt * 64 + lane];
        bf16x8 c2 = sA8[kt * 64 + lsw];
        #pragma unroll
        for (int r = 0; r < RPT; ++r) {
            f32x4 acc = {0.f, 0.f, 0.f, 0.f};
            acc = __builtin_amdgcn_mfma_f32_16x16x32_bf16(a_hm[r], c1, acc, 0, 0, 0); // hh'+mm'
            acc = __builtin_amdgcn_mfma_f32_16x16x32_bf16(a_hm[r], c2, acc, 0, 0, 0); // hm'+mh'
            #pragma unroll
            for (int i = 0; i < 4; ++i) best[r][i] = fmaxf(best[r][i], acc[i]);
        }
    }

    // reduce max over the 16 columns; one f32 store per row
    #pragma unroll
    for (int r = 0; r < RPT; ++r) {
        #pragma unroll
        for (int i = 0; i < 4; ++i) {
            float s = best[r][i];
            #pragma unroll
            for (int off = 1; off <= 8; off <<= 1)
                s = fmaxf(s, __shfl_xor(s, off, 64));
            if ((lane & 15) == 0) {
                int row = (rt0 + r) * 16 + (lane >> 4) * 4 + i;
                if (row < M_ROWS) pf[(size_t)row * NCHUNK + kc] = s;
            }
        }
    }
}

// ---------- Pass 2: exact rescore of candidate chunks + argmax ----------
// One wave per row. Candidate chunk: approx max >= gmax - M (provably contains
// the argmax). Exact fp32 dots, first-index tie-break (verified round 11).
__global__ __launch_bounds__(256) void argmax_kernel(const float* __restrict__ pf,
                                                     const float* __restrict__ Mg,
                                                     const float* __restrict__ Xf,
                                                     const float* __restrict__ CB,
                                                     int* __restrict__ out) {
    int t    = threadIdx.x;
    int lane = t & 63;
    int w    = t >> 6;
    int row  = blockIdx.x * 4 + w;    // < 16000 by grid

    float pv = pf[(size_t)row * NCHUNK + (lane & 31)];
    float gmax = pv;
    #pragma unroll
    for (int off = 1; off <= 16; off <<= 1)
        gmax = fmaxf(gmax, __shfl_xor(gmax, off, 64));
    float thr = gmax - Mg[row];

    float4 x0 = *reinterpret_cast<const float4*>(Xf + (size_t)row * E_DIM + 0);
    float4 x1 = *reinterpret_cast<const float4*>(Xf + (size_t)row * E_DIM + 4);
    float4 x2 = *reinterpret_cast<const float4*>(Xf + (size_t)row * E_DIM + 8);
    float4 x3 = *reinterpret_cast<const float4*>(Xf + (size_t)row * E_DIM + 12);

    float bs   = -3.0e38f;
    int   bidx = 0x7FFFFFFF;
    for (int kc = 0; kc < NCHUNK; ++kc) {
        float cm = __shfl(pv, kc, 64);
        if (cm >= thr) {
            #pragma unroll
            for (int j = 0; j < 4; ++j) {
                int cw = kc * 256 + j * 64 + lane;          // coalesced
                const float4* cp = reinterpret_cast<const float4*>(CB + (size_t)cw * E_DIM);
                float4 c0 = cp[0], c1 = cp[1], c2 = cp[2], c3 = cp[3];
                float s = x0.x * c0.x + x0.y * c0.y + x0.z * c0.z + x0.w * c0.w
                        + x1.x * c1.x + x1.y * c1.y + x1.z * c1.z + x1.w * c1.w
                        + x2.x * c2.x + x2.y * c2.y + x2.z * c2.z + x2.w * c2.w
                        + x3.x * c3.x + x3.y * c3.y + x3.z * c3.z + x3.w * c3.w;
                bool take = (s > bs) || (s == bs && cw < bidx);
                bs   = take ? s  : bs;
                bidx = take ? cw : bidx;
            }
        }
    }
    #pragma unroll
    for (int off = 1; off <= 32; off <<= 1) {
        float os = __shfl_xor(bs, off, 64);
        int   oi = __shfl_xor(bidx, off, 64);
        bool take = (os > bs) || (os == bs && oi < bidx);
        bs   = take ? os : bs;
        bidx = take ? oi : bidx;
    }
    if (lane == 0) out[row] = bidx;
}

extern "C" void kernel_launch(void* const* d_in, const int* in_sizes, int n_in,
                              void* d_out, int out_size, void* d_ws, size_t ws_size,
                              hipStream_t stream) {
    const float* hs = (const float*)d_in[0];   // [8,2000,320]
    const float* P  = (const float*)d_in[1];   // [1,320,16]
    const float* CB = (const float*)d_in[2];   // [1,8192,16]
    int* out = (int*)d_out;                    // [8,1,2000] int32

    char* ws = (char*)d_ws;
    unsigned short* Xa  = (unsigned short*)(ws + XA_OFF);
    unsigned short* CBa = (unsigned short*)(ws + CBA_OFF);
    float* Xf = (float*)(ws + XF_OFF);
    float* Mg = (float*)(ws + MG_OFF);
    float* pf = (float*)(ws + PF_OFF);

    prep_kernel<<<dim3(378), dim3(256), 0, stream>>>(hs, P, CB, Xa, Xf, Mg, CBa);
    score_kernel<<<dim3(NRB * NCHUNK), dim3(256), 0, stream>>>(Xa, CBa, pf);
    argmax_kernel<<<dim3(M_ROWS / 4), dim3(256), 0, stream>>>(pf, Mg, Xf, CB, out);
}